// Round 7
// baseline (304.262 us; speedup 1.0000x reference)
//
#include <hip/hip_runtime.h>
#include <hip/hip_bf16.h>

// ---------- types ----------
typedef __bf16    bf16x8_t __attribute__((ext_vector_type(8)));
typedef __bf16    bf16x4_t __attribute__((ext_vector_type(4)));
typedef float     f32x4_t  __attribute__((ext_vector_type(4)));
typedef _Float16  f16x8_t  __attribute__((ext_vector_type(8)));

static __device__ __forceinline__ f32x4_t mfma16(bf16x8_t a, bf16x8_t b, f32x4_t c) {
    return __builtin_amdgcn_mfma_f32_16x16x32_bf16(a, b, c, 0, 0, 0);
}

static __device__ __forceinline__ float redsum16(float v) {
#pragma unroll
    for (int off = 1; off < 16; off <<= 1) v += __shfl_xor(v, off);
    return v;
}

// async global->LDS 16B (m97 pattern); lds pointer must be wave-uniform
static __device__ __forceinline__ void async16(const __bf16* g, __bf16* l) {
    __builtin_amdgcn_global_load_lds(
        (const __attribute__((address_space(1))) unsigned int*)g,
        (__attribute__((address_space(3))) unsigned int*)l, 16, 0, 0);
}

// ---------- fused fp32 -> bf16 convert ----------
__global__ __launch_bounds__(256) void f2b_multi(const float* __restrict__ q,
                                                 const float* __restrict__ kv,
                                                 const float* __restrict__ wq,
                                                 const float* __restrict__ wk,
                                                 const float* __restrict__ wv,
                                                 const float* __restrict__ wo,
                                                 __bf16* __restrict__ qb,
                                                 __bf16* __restrict__ kvb,
                                                 __bf16* __restrict__ wqb,
                                                 __bf16* __restrict__ wkvb,
                                                 __bf16* __restrict__ wob,
                                                 float qscale) {
    int i = blockIdx.x * 256 + threadIdx.x;
    const float* src; __bf16* dst; int base; float scale = 1.0f;
    if (i < 1048576)      { src = q;  dst = qb;   base = 0; }
    else if (i < 3145728) { src = kv; dst = kvb;  base = 1048576; }
    else if (i < 3407872) { src = wq; dst = wqb;  base = 3145728; scale = qscale; }
    else if (i < 3670016) { src = wk; dst = wkvb; base = 3407872; }
    else if (i < 3932160) { src = wv; dst = wkvb + 1048576; base = 3670016; }
    else                  { src = wo; dst = wob;  base = 3932160; }
    int j = i - base;
    float4 v = reinterpret_cast<const float4*>(src)[j];
    bf16x4_t o;
    o[0] = (__bf16)(v.x * scale); o[1] = (__bf16)(v.y * scale);
    o[2] = (__bf16)(v.z * scale); o[3] = (__bf16)(v.w * scale);
    reinterpret_cast<bf16x4_t*>(dst)[j] = o;
}

// ---------- merged projection GEMM: Q + K + V in one launch ----------
// grid 1280: gid<256 -> Qp = qb*wqb^T (row-major out); else KV: Khd / Vhd layouts.
// K=1024. LDS-staged coalesced epilogues (each wave -> contiguous 8KB block / row chunks).
__global__ __launch_bounds__(256) void proj_kernel(const __bf16* __restrict__ qb,
                                                   const __bf16* __restrict__ wqb,
                                                   const __bf16* __restrict__ kvb,
                                                   const __bf16* __restrict__ wkvb,
                                                   __bf16* __restrict__ Qp,
                                                   __bf16* __restrict__ Khd,
                                                   __bf16* __restrict__ Vhd,
                                                   const float* __restrict__ imp) {
    __shared__ __bf16 As[128 * 32];
    __shared__ __bf16 Bs[128 * 32];
    __shared__ __bf16 Es[2][4096];

    const int gid = blockIdx.x;
    const __bf16 *A, *B;
    long m0, n0;
    int mode;   // 0=Q, 1=K-part, 2=V-part
    if (gid < 256) {
        m0 = (long)(gid >> 3) * 128; n0 = (long)(gid & 7) * 128;
        A = qb; B = wqb; mode = 0;
    } else {
        int g2 = gid - 256;
        m0 = (long)(g2 >> 4) * 128; n0 = (long)(g2 & 15) * 128;
        A = kvb; B = wkvb; mode = (n0 < 1024) ? 1 : 2;
    }

    const int t    = threadIdx.x;
    const int w    = t >> 6;
    const int lane = t & 63;
    const int quad = lane >> 4;
    const int mn   = lane & 15;
    const int wm   = (w & 1) * 64;
    const int wn   = (w >> 1) * 64;

    const int  srow = t >> 2;
    const int  scol = (t & 3) * 8;
    const __bf16* gA = A + (m0 + srow) * 1024 + scol;
    const __bf16* gB = B + (n0 + srow) * 1024 + scol;

    f32x4_t acc[4][4];
#pragma unroll
    for (int i = 0; i < 4; i++)
#pragma unroll
        for (int j = 0; j < 4; j++) acc[i][j] = (f32x4_t){0.f, 0.f, 0.f, 0.f};

    for (int k0 = 0; k0 < 1024; k0 += 32) {
        __syncthreads();
        async16(gA + k0,              &As[t * 8]);
        async16(gA + 64 * 1024 + k0,  &As[2048 + t * 8]);
        async16(gB + k0,              &Bs[t * 8]);
        async16(gB + 64 * 1024 + k0,  &Bs[2048 + t * 8]);
        __syncthreads();

        bf16x8_t af[4], bf[4];
#pragma unroll
        for (int i = 0; i < 4; i++)
            af[i] = *(const bf16x8_t*)&As[(wm + i * 16 + mn) * 32 + quad * 8];
#pragma unroll
        for (int j = 0; j < 4; j++)
            bf[j] = *(const bf16x8_t*)&Bs[(wn + j * 16 + mn) * 32 + quad * 8];
#pragma unroll
        for (int i = 0; i < 4; i++)
#pragma unroll
            for (int j = 0; j < 4; j++) acc[i][j] = mfma16(af[i], bf[j], acc[i][j]);
    }

    __syncthreads();   // done reading As/Bs -> reuse as epilogue staging
    __bf16* stg = (w == 0) ? As : (w == 1) ? Bs : Es[w - 2];
    // swizzled LDS addr: (row, col) -> row*64 + ((col>>3)^(row&7))*8 + (col&7)

    if (mode != 2) {
#pragma unroll
        for (int i = 0; i < 4; i++)
#pragma unroll
            for (int j = 0; j < 4; j++)
#pragma unroll
                for (int r = 0; r < 4; r++) {
                    int sl = i * 16 + quad * 4 + r;
                    int d  = j * 16 + mn;
                    stg[sl * 64 + (((d >> 3) ^ (sl & 7)) * 8) + (d & 7)] =
                        (__bf16)acc[i][j][r];
                }
    } else {
        // V: transpose+permute [d][p], p=(quad*4+r)*4+i, scale by clamped imp
        const int b_ = (int)((m0 + wm) >> 12);
#pragma unroll
        for (int r = 0; r < 4; r++) {
            float scl = fmaxf(imp[b_ * 16 + quad * 4 + r], 1e-6f);
#pragma unroll
            for (int j = 0; j < 4; j++) {
                bf16x4_t pk;
#pragma unroll
                for (int i = 0; i < 4; i++) pk[i] = (__bf16)(acc[i][j][r] * scl);
                int d  = j * 16 + mn;
                int p0 = (quad * 4 + r) * 4;
                *(bf16x4_t*)&stg[d * 64 + (((p0 >> 3) ^ (d & 7)) * 8) + (p0 & 7)] = pk;
            }
        }
    }

    if (mode == 0) {
        __bf16* Cg = Qp + (m0 + wm) * 1024 + (n0 + wn);
#pragma unroll
        for (int it = 0; it < 8; it++) {
            int rowL = it * 8 + (lane >> 3);
            int cb   = lane & 7;
            bf16x8_t vv = *(const bf16x8_t*)&stg[rowL * 64 + ((cb ^ (rowL & 7)) * 8)];
            *(bf16x8_t*)&Cg[(long)rowL * 1024 + cb * 8] = vv;
        }
    } else {
        const int b_    = (int)((m0 + wm) >> 12);
        const int sbase = (int)((m0 + wm) & 4095);
        __bf16* dst;
        if (mode == 1) {
            int h_ = (int)((n0 + wn) >> 6);
            dst = Khd + (long)(b_ * 16 + h_) * 262144 + (long)sbase * 64;
        } else {
            int h_ = (int)((n0 + wn) >> 6) - 16;
            dst = Vhd + (long)(b_ * 16 + h_) * 262144 + (long)(sbase >> 6) * 4096;
        }
#pragma unroll
        for (int it = 0; it < 8; it++) {
            int rowL = it * 8 + (lane >> 3);
            int cb   = lane & 7;
            bf16x8_t vv = *(const bf16x8_t*)&stg[rowL * 64 + ((cb ^ (rowL & 7)) * 8)];
            *(bf16x8_t*)&dst[rowL * 64 + cb * 8] = vv;
        }
    }
}

// ---------- flash attention: double-buffered LDS K/V staging ----------
// 1D grid 1024, XCD-swizzled: gid = (bh&7) | qt<<3 | sp<<7 | (bh>>3)<<8.
// One barrier per iter; prefetch tile i+1 into alternate buffer overlaps compute of i.
__global__ __launch_bounds__(256) void attn_kernel(const __bf16* __restrict__ Qp,
                                                   const __bf16* __restrict__ Kh,
                                                   const __bf16* __restrict__ Vh,
                                                   const float* __restrict__ imp,
                                                   _Float16* __restrict__ Op,
                                                   float* __restrict__ Lp) {
    const int gid = blockIdx.x;
    const int qt  = (gid >> 3) & 15;
    const int sp  = (gid >> 7) & 1;
    const int bh  = ((gid >> 8) << 3) | (gid & 7);
    const int b   = bh >> 4;
    const int h   = bh & 15;
    const int t    = threadIdx.x;
    const int w    = t >> 6;
    const int lane = t & 63;
    const int quad = lane >> 4;
    const int mn   = lane & 15;

    __shared__ __bf16 Ks[2][4096];
    __shared__ __bf16 Vs[2][4096];
    __shared__ __bf16 Ps[4][32][72];

    const long qrow0 = (long)b * 2048 + qt * 128 + w * 32;
    const __bf16* Kb = Kh + (long)bh * 262144;
    const __bf16* Vb = Vh + (long)bh * 262144;

    const int r8 = lane >> 3;
    const int cs = (lane & 7) ^ r8;
    const int srcoff0 = (0 * 4 + w) * 512 + r8 * 64 + cs * 8;
    const int srcoff1 = (1 * 4 + w) * 512 + r8 * 64 + cs * 8;

    bf16x8_t aq[2][2];
#pragma unroll
    for (int rt = 0; rt < 2; rt++)
#pragma unroll
        for (int x = 0; x < 2; x++)
            aq[rt][x] = *(const bf16x8_t*)&Qp[(qrow0 + rt * 16 + mn) * 1024 + h * 64 + x * 32 + quad * 8];

    const float impc = fmaxf(imp[b * 16 + mn], 1e-6f);

    float lpart[2][4];
    f32x4_t o[2][4];
#pragma unroll
    for (int rt = 0; rt < 2; rt++)
#pragma unroll
        for (int r = 0; r < 4; r++) lpart[rt][r] = 0.f;
#pragma unroll
    for (int rt = 0; rt < 2; rt++)
#pragma unroll
        for (int dt = 0; dt < 4; dt++) o[rt][dt] = (f32x4_t){0.f, 0.f, 0.f, 0.f};

    // prologue: stage first tile into buffer 0
    {
        const long kbase = (long)(sp * 32) * 4096;
        async16(Kb + kbase + srcoff0, &Ks[0][(0 * 4 + w) * 512]);
        async16(Kb + kbase + srcoff1, &Ks[0][(1 * 4 + w) * 512]);
        async16(Vb + kbase + srcoff0, &Vs[0][(0 * 4 + w) * 512]);
        async16(Vb + kbase + srcoff1, &Vs[0][(1 * 4 + w) * 512]);
    }

    for (int ii = 0; ii < 32; ii++) {
        const int bi = ii & 1;
        __syncthreads();   // vmcnt+lgkm drained -> buf[bi] visible; prior reads of buf[bi^1] done

        if (ii + 1 < 32) {   // prefetch next tile into alternate buffer
            const long kbase = (long)(sp * 32 + ii + 1) * 4096;
            async16(Kb + kbase + srcoff0, &Ks[bi ^ 1][(0 * 4 + w) * 512]);
            async16(Kb + kbase + srcoff1, &Ks[bi ^ 1][(1 * 4 + w) * 512]);
            async16(Vb + kbase + srcoff0, &Vs[bi ^ 1][(0 * 4 + w) * 512]);
            async16(Vb + kbase + srcoff1, &Vs[bi ^ 1][(1 * 4 + w) * 512]);
        }

        // ---- QK^T from Ks[bi] ----
        f32x4_t sc[2][4];
        {
            bf16x8_t bk0[4], bk1[4];
#pragma unroll
            for (int ct = 0; ct < 4; ct++) {
                int s  = ct * 16 + mn;
                int c0 = (quad ^ (s & 7)) * 8;
                bk0[ct] = *(const bf16x8_t*)&Ks[bi][s * 64 + c0];
                bk1[ct] = *(const bf16x8_t*)&Ks[bi][s * 64 + (c0 ^ 32)];
            }
#pragma unroll
            for (int rt = 0; rt < 2; rt++) {
#pragma unroll
                for (int ct = 0; ct < 4; ct++) sc[rt][ct] = (f32x4_t){0.f, 0.f, 0.f, 0.f};
#pragma unroll
                for (int ct = 0; ct < 4; ct++) {
                    sc[rt][ct] = mfma16(aq[rt][0], bk0[ct], sc[rt][ct]);
                    sc[rt][ct] = mfma16(aq[rt][1], bk1[ct], sc[rt][ct]);
                }
            }
        }

        // ---- softmax (shuffle-free, fixed m=0) ----
#pragma unroll
        for (int rt = 0; rt < 2; rt++)
#pragma unroll
            for (int r = 0; r < 4; r++) {
                float p0 = __builtin_amdgcn_exp2f(sc[rt][0][r]);
                float p1 = __builtin_amdgcn_exp2f(sc[rt][1][r]);
                float p2 = __builtin_amdgcn_exp2f(sc[rt][2][r]);
                float p3 = __builtin_amdgcn_exp2f(sc[rt][3][r]);
                lpart[rt][r] += (p0 + p1) + (p2 + p3);
                bf16x4_t pk;
                pk[0] = (__bf16)p0; pk[1] = (__bf16)p1;
                pk[2] = (__bf16)p2; pk[3] = (__bf16)p3;
                *(bf16x4_t*)&Ps[w][rt * 16 + quad * 4 + r][mn * 4] = pk;
            }

        // ---- PV from Vs[bi] ----
        {
            bf16x8_t bv0[4], bv1[4];
#pragma unroll
            for (int dt = 0; dt < 4; dt++) {
                int d  = dt * 16 + mn;
                int c0 = (quad ^ (d & 7)) * 8;
                bv0[dt] = *(const bf16x8_t*)&Vs[bi][d * 64 + c0];
                bv1[dt] = *(const bf16x8_t*)&Vs[bi][d * 64 + (c0 ^ 32)];
            }
#pragma unroll
            for (int rt = 0; rt < 2; rt++) {
                bf16x8_t ap0 = *(const bf16x8_t*)&Ps[w][rt * 16 + mn][quad * 8];
                bf16x8_t ap1 = *(const bf16x8_t*)&Ps[w][rt * 16 + mn][32 + quad * 8];
#pragma unroll
                for (int dt = 0; dt < 4; dt++) {
                    o[rt][dt] = mfma16(ap0, bv0[dt], o[rt][dt]);
                    o[rt][dt] = mfma16(ap1, bv1[dt], o[rt][dt]);
                }
            }
        }
    }

    // epilogue: per-row l, unnormalized fp16 partials
#pragma unroll
    for (int rt = 0; rt < 2; rt++)
#pragma unroll
        for (int r = 0; r < 4; r++) {
            float l = redsum16(lpart[rt][r] * impc);
            long row = qrow0 + rt * 16 + quad * 4 + r;
            if (mn == 0) Lp[((long)sp * 4096 + row) * 16 + h] = l;
#pragma unroll
            for (int dt = 0; dt < 4; dt++)
                Op[((long)sp * 4096 + row) * 1024 + h * 64 + dt * 16 + mn] =
                    (_Float16)o[rt][dt][r];
        }
}

// ---------- combine: Y = (o0+o1)/(l0+l1) ----------
__global__ __launch_bounds__(256) void combine_kernel(const _Float16* __restrict__ Op,
                                                      const float* __restrict__ Lp,
                                                      __bf16* __restrict__ Y) {
    int tid = blockIdx.x * 256 + threadIdx.x;
    int row = tid >> 7;
    int cg  = tid & 127;
    int h   = cg >> 3;
    f16x8_t o0 = *(const f16x8_t*)&Op[(long)row * 1024 + cg * 8];
    f16x8_t o1 = *(const f16x8_t*)&Op[(long)(4096 + row) * 1024 + cg * 8];
    float inv = 1.0f / (Lp[row * 16 + h] + Lp[(4096 + row) * 16 + h]);
    bf16x8_t y;
#pragma unroll
    for (int j = 0; j < 8; j++) y[j] = (__bf16)(((float)o0[j] + (float)o1[j]) * inv);
    *(bf16x8_t*)&Y[(long)row * 1024 + cg * 8] = y;
}

// ---------- output GEMM: C fp32 = A[M,K] * B[N,K]^T, direct dword stores ----------
__global__ __launch_bounds__(256) void gemm_out_kernel(const __bf16* __restrict__ A,
                                                       const __bf16* __restrict__ B,
                                                       float* __restrict__ C) {
    __shared__ __bf16 As[128 * 32];
    __shared__ __bf16 Bs[128 * 32];

    const int t    = threadIdx.x;
    const int w    = t >> 6;
    const int lane = t & 63;
    const int quad = lane >> 4;
    const int mn   = lane & 15;
    const int wm   = (w & 1) * 64;
    const int wn   = (w >> 1) * 64;
    const long m0  = (long)blockIdx.y * 128;
    const long n0  = (long)blockIdx.x * 128;

    const int  srow = t >> 2;
    const int  scol = (t & 3) * 8;
    const __bf16* gA = A + (m0 + srow) * 1024 + scol;
    const __bf16* gB = B + (n0 + srow) * 1024 + scol;

    f32x4_t acc[4][4];
#pragma unroll
    for (int i = 0; i < 4; i++)
#pragma unroll
        for (int j = 0; j < 4; j++) acc[i][j] = (f32x4_t){0.f, 0.f, 0.f, 0.f};

    for (int k0 = 0; k0 < 1024; k0 += 32) {
        __syncthreads();
        async16(gA + k0,             &As[t * 8]);
        async16(gA + 64 * 1024 + k0, &As[2048 + t * 8]);
        async16(gB + k0,             &Bs[t * 8]);
        async16(gB + 64 * 1024 + k0, &Bs[2048 + t * 8]);
        __syncthreads();

        bf16x8_t af[4], bf[4];
#pragma unroll
        for (int i = 0; i < 4; i++)
            af[i] = *(const bf16x8_t*)&As[(wm + i * 16 + mn) * 32 + quad * 8];
#pragma unroll
        for (int j = 0; j < 4; j++)
            bf[j] = *(const bf16x8_t*)&Bs[(wn + j * 16 + mn) * 32 + quad * 8];
#pragma unroll
        for (int i = 0; i < 4; i++)
#pragma unroll
            for (int j = 0; j < 4; j++) acc[i][j] = mfma16(af[i], bf[j], acc[i][j]);
    }

#pragma unroll
    for (int i = 0; i < 4; i++)
#pragma unroll
        for (int j = 0; j < 4; j++)
#pragma unroll
            for (int r = 0; r < 4; r++) {
                long row = m0 + wm + i * 16 + quad * 4 + r;
                long col = n0 + wn + j * 16 + mn;
                C[row * 1024 + col] = acc[i][j][r];
            }
}

// ---------- launch ----------
extern "C" void kernel_launch(void* const* d_in, const int* in_sizes, int n_in,
                              void* d_out, int out_size, void* d_ws, size_t ws_size,
                              hipStream_t stream) {
    const float* q_f  = (const float*)d_in[0];
    const float* kv_f = (const float*)d_in[1];
    const float* imp  = (const float*)d_in[2];
    const float* wq_f = (const float*)d_in[3];
    const float* wk_f = (const float*)d_in[4];
    const float* wv_f = (const float*)d_in[5];
    const float* wo_f = (const float*)d_in[6];

    char* ws = (char*)d_ws;
    const size_t MB = 1ull << 20;
    __bf16*   qb    = (__bf16*)(ws + 0);            // 8 MB   (stage A)
    __bf16*   kvb   = (__bf16*)(ws + 8 * MB);       // 16 MB  (stage A)
    __bf16*   wqb   = (__bf16*)(ws + 24 * MB);      // 2 MB   (stage A)
    __bf16*   wkvb  = (__bf16*)(ws + 26 * MB);      // 4 MB   (stage A)
    _Float16* Opart = (_Float16*)(ws + 0);          // 16 MB  (stage B)
    float*    Lpart = (float*)(ws + 16 * MB);       // 0.5 MB (stage B)
    __bf16*   Yb    = (__bf16*)(ws + 17 * MB);      // 8 MB   (stage B)
    __bf16*   wob   = (__bf16*)(ws + 30 * MB);      // 2 MB
    __bf16*   Qp    = (__bf16*)(ws + 32 * MB);      // 8 MB
    __bf16*   Khd   = (__bf16*)(ws + 40 * MB);      // 16 MB
    __bf16*   Vhd   = (__bf16*)(ws + 56 * MB);      // 16 MB

    const float QSCALE = 0.125f * 1.4426950408889634f;

    f2b_multi<<<16384, 256, 0, stream>>>(q_f, kv_f, wq_f, wk_f, wv_f, wo_f,
                                         qb, kvb, wqb, wkvb, wob, QSCALE);

    proj_kernel<<<1280, 256, 0, stream>>>(qb, wqb, kvb, wkvb, Qp, Khd, Vhd, imp);

    attn_kernel<<<1024, 256, 0, stream>>>(Qp, Khd, Vhd, imp, Opart, Lpart);
    combine_kernel<<<2048, 256, 0, stream>>>(Opart, Lpart, Yb);

    gemm_out_kernel<<<dim3(8, 32), 256, 0, stream>>>(Yb, wob, (float*)d_out);
}

// Round 8
// 288.654 us; speedup vs baseline: 1.0541x; 1.0541x over previous
//
#include <hip/hip_runtime.h>
#include <hip/hip_bf16.h>

// ---------- types ----------
typedef __bf16    bf16x8_t __attribute__((ext_vector_type(8)));
typedef __bf16    bf16x4_t __attribute__((ext_vector_type(4)));
typedef float     f32x4_t  __attribute__((ext_vector_type(4)));
typedef _Float16  f16x8_t  __attribute__((ext_vector_type(8)));

static __device__ __forceinline__ f32x4_t mfma16(bf16x8_t a, bf16x8_t b, f32x4_t c) {
    return __builtin_amdgcn_mfma_f32_16x16x32_bf16(a, b, c, 0, 0, 0);
}

static __device__ __forceinline__ float redsum16(float v) {
#pragma unroll
    for (int off = 1; off < 16; off <<= 1) v += __shfl_xor(v, off);
    return v;
}

// async global->LDS 16B (m97 pattern); lds pointer must be wave-uniform
static __device__ __forceinline__ void async16(const __bf16* g, __bf16* l) {
    __builtin_amdgcn_global_load_lds(
        (const __attribute__((address_space(1))) unsigned int*)g,
        (__attribute__((address_space(3))) unsigned int*)l, 16, 0, 0);
}

// ---------- fused fp32 -> bf16 convert ----------
__global__ __launch_bounds__(256) void f2b_multi(const float* __restrict__ q,
                                                 const float* __restrict__ kv,
                                                 const float* __restrict__ wq,
                                                 const float* __restrict__ wk,
                                                 const float* __restrict__ wv,
                                                 const float* __restrict__ wo,
                                                 __bf16* __restrict__ qb,
                                                 __bf16* __restrict__ kvb,
                                                 __bf16* __restrict__ wqb,
                                                 __bf16* __restrict__ wkvb,
                                                 __bf16* __restrict__ wob,
                                                 float qscale) {
    int i = blockIdx.x * 256 + threadIdx.x;
    const float* src; __bf16* dst; int base; float scale = 1.0f;
    if (i < 1048576)      { src = q;  dst = qb;   base = 0; }
    else if (i < 3145728) { src = kv; dst = kvb;  base = 1048576; }
    else if (i < 3407872) { src = wq; dst = wqb;  base = 3145728; scale = qscale; }
    else if (i < 3670016) { src = wk; dst = wkvb; base = 3407872; }
    else if (i < 3932160) { src = wv; dst = wkvb + 1048576; base = 3670016; }
    else                  { src = wo; dst = wob;  base = 3932160; }
    int j = i - base;
    float4 v = reinterpret_cast<const float4*>(src)[j];
    bf16x4_t o;
    o[0] = (__bf16)(v.x * scale); o[1] = (__bf16)(v.y * scale);
    o[2] = (__bf16)(v.z * scale); o[3] = (__bf16)(v.w * scale);
    reinterpret_cast<bf16x4_t*>(dst)[j] = o;
}

// ---------- merged projection GEMM: Q + K + V in one launch ----------
// grid 1280: gid<256 -> Qp = qb*wqb^T (row-major out); else KV: Khd / Vhd layouts.
__global__ __launch_bounds__(256) void proj_kernel(const __bf16* __restrict__ qb,
                                                   const __bf16* __restrict__ wqb,
                                                   const __bf16* __restrict__ kvb,
                                                   const __bf16* __restrict__ wkvb,
                                                   __bf16* __restrict__ Qp,
                                                   __bf16* __restrict__ Khd,
                                                   __bf16* __restrict__ Vhd,
                                                   const float* __restrict__ imp) {
    __shared__ __bf16 As[128 * 32];
    __shared__ __bf16 Bs[128 * 32];
    __shared__ __bf16 Es[2][4096];

    const int gid = blockIdx.x;
    const __bf16 *A, *B;
    long m0, n0;
    int mode;   // 0=Q, 1=K-part, 2=V-part
    if (gid < 256) {
        m0 = (long)(gid >> 3) * 128; n0 = (long)(gid & 7) * 128;
        A = qb; B = wqb; mode = 0;
    } else {
        int g2 = gid - 256;
        m0 = (long)(g2 >> 4) * 128; n0 = (long)(g2 & 15) * 128;
        A = kvb; B = wkvb; mode = (n0 < 1024) ? 1 : 2;
    }

    const int t    = threadIdx.x;
    const int w    = t >> 6;
    const int lane = t & 63;
    const int quad = lane >> 4;
    const int mn   = lane & 15;
    const int wm   = (w & 1) * 64;
    const int wn   = (w >> 1) * 64;

    const int  srow = t >> 2;
    const int  scol = (t & 3) * 8;
    const __bf16* gA = A + (m0 + srow) * 1024 + scol;
    const __bf16* gB = B + (n0 + srow) * 1024 + scol;

    f32x4_t acc[4][4];
#pragma unroll
    for (int i = 0; i < 4; i++)
#pragma unroll
        for (int j = 0; j < 4; j++) acc[i][j] = (f32x4_t){0.f, 0.f, 0.f, 0.f};

    for (int k0 = 0; k0 < 1024; k0 += 32) {
        __syncthreads();
        async16(gA + k0,              &As[t * 8]);
        async16(gA + 64 * 1024 + k0,  &As[2048 + t * 8]);
        async16(gB + k0,              &Bs[t * 8]);
        async16(gB + 64 * 1024 + k0,  &Bs[2048 + t * 8]);
        __syncthreads();

        bf16x8_t af[4], bf[4];
#pragma unroll
        for (int i = 0; i < 4; i++)
            af[i] = *(const bf16x8_t*)&As[(wm + i * 16 + mn) * 32 + quad * 8];
#pragma unroll
        for (int j = 0; j < 4; j++)
            bf[j] = *(const bf16x8_t*)&Bs[(wn + j * 16 + mn) * 32 + quad * 8];
#pragma unroll
        for (int i = 0; i < 4; i++)
#pragma unroll
            for (int j = 0; j < 4; j++) acc[i][j] = mfma16(af[i], bf[j], acc[i][j]);
    }

    __syncthreads();   // done reading As/Bs -> reuse as epilogue staging
    __bf16* stg = (w == 0) ? As : (w == 1) ? Bs : Es[w - 2];
    // swizzled LDS addr: (row, col) -> row*64 + ((col>>3)^(row&7))*8 + (col&7)

    if (mode != 2) {
#pragma unroll
        for (int i = 0; i < 4; i++)
#pragma unroll
            for (int j = 0; j < 4; j++)
#pragma unroll
                for (int r = 0; r < 4; r++) {
                    int sl = i * 16 + quad * 4 + r;
                    int d  = j * 16 + mn;
                    stg[sl * 64 + (((d >> 3) ^ (sl & 7)) * 8) + (d & 7)] =
                        (__bf16)acc[i][j][r];
                }
    } else {
        // V: transpose+permute [d][p], p=(quad*4+r)*4+i, scale by clamped imp
        const int b_ = (int)((m0 + wm) >> 12);
#pragma unroll
        for (int r = 0; r < 4; r++) {
            float scl = fmaxf(imp[b_ * 16 + quad * 4 + r], 1e-6f);
#pragma unroll
            for (int j = 0; j < 4; j++) {
                bf16x4_t pk;
#pragma unroll
                for (int i = 0; i < 4; i++) pk[i] = (__bf16)(acc[i][j][r] * scl);
                int d  = j * 16 + mn;
                int p0 = (quad * 4 + r) * 4;
                *(bf16x4_t*)&stg[d * 64 + (((p0 >> 3) ^ (d & 7)) * 8) + (p0 & 7)] = pk;
            }
        }
    }

    if (mode == 0) {
        __bf16* Cg = Qp + (m0 + wm) * 1024 + (n0 + wn);
#pragma unroll
        for (int it = 0; it < 8; it++) {
            int rowL = it * 8 + (lane >> 3);
            int cb   = lane & 7;
            bf16x8_t vv = *(const bf16x8_t*)&stg[rowL * 64 + ((cb ^ (rowL & 7)) * 8)];
            *(bf16x8_t*)&Cg[(long)rowL * 1024 + cb * 8] = vv;
        }
    } else {
        const int b_    = (int)((m0 + wm) >> 12);
        const int sbase = (int)((m0 + wm) & 4095);
        __bf16* dst;
        if (mode == 1) {
            int h_ = (int)((n0 + wn) >> 6);
            dst = Khd + (long)(b_ * 16 + h_) * 262144 + (long)sbase * 64;
        } else {
            int h_ = (int)((n0 + wn) >> 6) - 16;
            dst = Vhd + (long)(b_ * 16 + h_) * 262144 + (long)(sbase >> 6) * 4096;
        }
#pragma unroll
        for (int it = 0; it < 8; it++) {
            int rowL = it * 8 + (lane >> 3);
            int cb   = lane & 7;
            bf16x8_t vv = *(const bf16x8_t*)&stg[rowL * 64 + ((cb ^ (rowL & 7)) * 8)];
            *(bf16x8_t*)&dst[rowL * 64 + cb * 8] = vv;
        }
    }
}

// ---------- flash attention: single-buffered LDS K/V staging (R6 config) ----------
// 1D grid 1024, XCD-swizzled: gid = (bh&7) | qt<<3 | sp<<7 | (bh>>3)<<8.
__global__ __launch_bounds__(256, 4) void attn_kernel(const __bf16* __restrict__ Qp,
                                                      const __bf16* __restrict__ Kh,
                                                      const __bf16* __restrict__ Vh,
                                                      const float* __restrict__ imp,
                                                      _Float16* __restrict__ Op,
                                                      float* __restrict__ Lp) {
    const int gid = blockIdx.x;
    const int qt  = (gid >> 3) & 15;
    const int sp  = (gid >> 7) & 1;
    const int bh  = ((gid >> 8) << 3) | (gid & 7);
    const int b   = bh >> 4;
    const int h   = bh & 15;
    const int t    = threadIdx.x;
    const int w    = t >> 6;
    const int lane = t & 63;
    const int quad = lane >> 4;
    const int mn   = lane & 15;

    __shared__ __bf16 Ks[64 * 64];
    __shared__ __bf16 Vs[64 * 64];
    __shared__ __bf16 Ps[4][32][72];

    const long qrow0 = (long)b * 2048 + qt * 128 + w * 32;
    const __bf16* Kb = Kh + (long)bh * 262144;
    const __bf16* Vb = Vh + (long)bh * 262144;

    const int r8 = lane >> 3;
    const int cs = (lane & 7) ^ r8;
    const int srcoff0 = (0 * 4 + w) * 512 + r8 * 64 + cs * 8;
    const int srcoff1 = (1 * 4 + w) * 512 + r8 * 64 + cs * 8;
    __bf16* ldsK0 = Ks + (0 * 4 + w) * 512;
    __bf16* ldsK1 = Ks + (1 * 4 + w) * 512;
    __bf16* ldsV0 = Vs + (0 * 4 + w) * 512;
    __bf16* ldsV1 = Vs + (1 * 4 + w) * 512;

    bf16x8_t aq[2][2];
#pragma unroll
    for (int rt = 0; rt < 2; rt++)
#pragma unroll
        for (int x = 0; x < 2; x++)
            aq[rt][x] = *(const bf16x8_t*)&Qp[(qrow0 + rt * 16 + mn) * 1024 + h * 64 + x * 32 + quad * 8];

    const float impc = fmaxf(imp[b * 16 + mn], 1e-6f);

    float lpart[2][4];
    f32x4_t o[2][4];
#pragma unroll
    for (int rt = 0; rt < 2; rt++)
#pragma unroll
        for (int r = 0; r < 4; r++) lpart[rt][r] = 0.f;
#pragma unroll
    for (int rt = 0; rt < 2; rt++)
#pragma unroll
        for (int dt = 0; dt < 4; dt++) o[rt][dt] = (f32x4_t){0.f, 0.f, 0.f, 0.f};

    for (int st = sp * 32; st < sp * 32 + 32; st++) {
        const long kbase = (long)st * 4096;
        __syncthreads();
        async16(Kb + kbase + srcoff0, ldsK0);
        async16(Kb + kbase + srcoff1, ldsK1);
        async16(Vb + kbase + srcoff0, ldsV0);
        async16(Vb + kbase + srcoff1, ldsV1);
        __syncthreads();

        f32x4_t sc[2][4];
        {
            bf16x8_t bk0[4], bk1[4];
#pragma unroll
            for (int ct = 0; ct < 4; ct++) {
                int s  = ct * 16 + mn;
                int c0 = (quad ^ (s & 7)) * 8;
                bk0[ct] = *(const bf16x8_t*)&Ks[s * 64 + c0];
                bk1[ct] = *(const bf16x8_t*)&Ks[s * 64 + (c0 ^ 32)];
            }
#pragma unroll
            for (int rt = 0; rt < 2; rt++) {
#pragma unroll
                for (int ct = 0; ct < 4; ct++) sc[rt][ct] = (f32x4_t){0.f, 0.f, 0.f, 0.f};
#pragma unroll
                for (int ct = 0; ct < 4; ct++) {
                    sc[rt][ct] = mfma16(aq[rt][0], bk0[ct], sc[rt][ct]);
                    sc[rt][ct] = mfma16(aq[rt][1], bk1[ct], sc[rt][ct]);
                }
            }
        }

#pragma unroll
        for (int rt = 0; rt < 2; rt++)
#pragma unroll
            for (int r = 0; r < 4; r++) {
                float p0 = __builtin_amdgcn_exp2f(sc[rt][0][r]);
                float p1 = __builtin_amdgcn_exp2f(sc[rt][1][r]);
                float p2 = __builtin_amdgcn_exp2f(sc[rt][2][r]);
                float p3 = __builtin_amdgcn_exp2f(sc[rt][3][r]);
                lpart[rt][r] += (p0 + p1) + (p2 + p3);
                bf16x4_t pk;
                pk[0] = (__bf16)p0; pk[1] = (__bf16)p1;
                pk[2] = (__bf16)p2; pk[3] = (__bf16)p3;
                *(bf16x4_t*)&Ps[w][rt * 16 + quad * 4 + r][mn * 4] = pk;
            }

        {
            bf16x8_t bv0[4], bv1[4];
#pragma unroll
            for (int dt = 0; dt < 4; dt++) {
                int d  = dt * 16 + mn;
                int c0 = (quad ^ (d & 7)) * 8;
                bv0[dt] = *(const bf16x8_t*)&Vs[d * 64 + c0];
                bv1[dt] = *(const bf16x8_t*)&Vs[d * 64 + (c0 ^ 32)];
            }
#pragma unroll
            for (int rt = 0; rt < 2; rt++) {
                bf16x8_t ap0 = *(const bf16x8_t*)&Ps[w][rt * 16 + mn][quad * 8];
                bf16x8_t ap1 = *(const bf16x8_t*)&Ps[w][rt * 16 + mn][32 + quad * 8];
#pragma unroll
                for (int dt = 0; dt < 4; dt++) {
                    o[rt][dt] = mfma16(ap0, bv0[dt], o[rt][dt]);
                    o[rt][dt] = mfma16(ap1, bv1[dt], o[rt][dt]);
                }
            }
        }
    }

#pragma unroll
    for (int rt = 0; rt < 2; rt++)
#pragma unroll
        for (int r = 0; r < 4; r++) {
            float l = redsum16(lpart[rt][r] * impc);
            long row = qrow0 + rt * 16 + quad * 4 + r;
            if (mn == 0) Lp[((long)sp * 4096 + row) * 16 + h] = l;
#pragma unroll
            for (int dt = 0; dt < 4; dt++)
                Op[((long)sp * 4096 + row) * 1024 + h * 64 + dt * 16 + mn] =
                    (_Float16)o[rt][dt][r];
        }
}

// ---------- combine: Y = (o0+o1)/(l0+l1) ----------
__global__ __launch_bounds__(256) void combine_kernel(const _Float16* __restrict__ Op,
                                                      const float* __restrict__ Lp,
                                                      __bf16* __restrict__ Y) {
    int tid = blockIdx.x * 256 + threadIdx.x;
    int row = tid >> 7;
    int cg  = tid & 127;
    int h   = cg >> 3;
    f16x8_t o0 = *(const f16x8_t*)&Op[(long)row * 1024 + cg * 8];
    f16x8_t o1 = *(const f16x8_t*)&Op[(long)(4096 + row) * 1024 + cg * 8];
    float inv = 1.0f / (Lp[row * 16 + h] + Lp[(4096 + row) * 16 + h]);
    bf16x8_t y;
#pragma unroll
    for (int j = 0; j < 8; j++) y[j] = (__bf16)(((float)o0[j] + (float)o1[j]) * inv);
    *(bf16x8_t*)&Y[(long)row * 1024 + cg * 8] = y;
}

// ---------- output GEMM, split-K x2: P[kh] = A[M, kh-half] * B[N, kh-half]^T ----------
// grid dim3(16, 32): kh = blockIdx.x>>3, n-tile = blockIdx.x&7, m-tile = blockIdx.y.
__global__ __launch_bounds__(256) void gemm_out_kernel(const __bf16* __restrict__ A,
                                                       const __bf16* __restrict__ B,
                                                       float* __restrict__ P) {
    __shared__ __bf16 As[128 * 32];
    __shared__ __bf16 Bs[128 * 32];

    const int  kh = blockIdx.x >> 3;
    const long n0 = (long)(blockIdx.x & 7) * 128;
    const long m0 = (long)blockIdx.y * 128;
    const int  kb = kh * 512;
    float* C = P + (long)kh * 4194304;

    const int t    = threadIdx.x;
    const int w    = t >> 6;
    const int lane = t & 63;
    const int quad = lane >> 4;
    const int mn   = lane & 15;
    const int wm   = (w & 1) * 64;
    const int wn   = (w >> 1) * 64;

    const int  srow = t >> 2;
    const int  scol = (t & 3) * 8;
    const __bf16* gA = A + (m0 + srow) * 1024 + kb + scol;
    const __bf16* gB = B + (n0 + srow) * 1024 + kb + scol;

    f32x4_t acc[4][4];
#pragma unroll
    for (int i = 0; i < 4; i++)
#pragma unroll
        for (int j = 0; j < 4; j++) acc[i][j] = (f32x4_t){0.f, 0.f, 0.f, 0.f};

    for (int k0 = 0; k0 < 512; k0 += 32) {
        __syncthreads();
        async16(gA + k0,             &As[t * 8]);
        async16(gA + 64 * 1024 + k0, &As[2048 + t * 8]);
        async16(gB + k0,             &Bs[t * 8]);
        async16(gB + 64 * 1024 + k0, &Bs[2048 + t * 8]);
        __syncthreads();

        bf16x8_t af[4], bf[4];
#pragma unroll
        for (int i = 0; i < 4; i++)
            af[i] = *(const bf16x8_t*)&As[(wm + i * 16 + mn) * 32 + quad * 8];
#pragma unroll
        for (int j = 0; j < 4; j++)
            bf[j] = *(const bf16x8_t*)&Bs[(wn + j * 16 + mn) * 32 + quad * 8];
#pragma unroll
        for (int i = 0; i < 4; i++)
#pragma unroll
            for (int j = 0; j < 4; j++) acc[i][j] = mfma16(af[i], bf[j], acc[i][j]);
    }

#pragma unroll
    for (int i = 0; i < 4; i++)
#pragma unroll
        for (int j = 0; j < 4; j++)
#pragma unroll
            for (int r = 0; r < 4; r++) {
                long row = m0 + wm + i * 16 + quad * 4 + r;
                long col = n0 + wn + j * 16 + mn;
                C[row * 1024 + col] = acc[i][j][r];
            }
}

// ---------- combine2: out = P0 + P1 (fp32 float4) ----------
__global__ __launch_bounds__(256) void combine2_kernel(const float* __restrict__ P0,
                                                       const float* __restrict__ P1,
                                                       float* __restrict__ out) {
    int i = blockIdx.x * 256 + threadIdx.x;   // float4 index, 0..1048575
    float4 a = reinterpret_cast<const float4*>(P0)[i];
    float4 b = reinterpret_cast<const float4*>(P1)[i];
    float4 c; c.x = a.x + b.x; c.y = a.y + b.y; c.z = a.z + b.z; c.w = a.w + b.w;
    reinterpret_cast<float4*>(out)[i] = c;
}

// ---------- launch ----------
extern "C" void kernel_launch(void* const* d_in, const int* in_sizes, int n_in,
                              void* d_out, int out_size, void* d_ws, size_t ws_size,
                              hipStream_t stream) {
    const float* q_f  = (const float*)d_in[0];
    const float* kv_f = (const float*)d_in[1];
    const float* imp  = (const float*)d_in[2];
    const float* wq_f = (const float*)d_in[3];
    const float* wk_f = (const float*)d_in[4];
    const float* wv_f = (const float*)d_in[5];
    const float* wo_f = (const float*)d_in[6];

    char* ws = (char*)d_ws;
    const size_t MB = 1ull << 20;
    __bf16*   qb    = (__bf16*)(ws + 0);            // 8 MB   (stage A)
    __bf16*   kvb   = (__bf16*)(ws + 8 * MB);       // 16 MB  (stage A)
    __bf16*   wqb   = (__bf16*)(ws + 24 * MB);      // 2 MB   (stage A)
    __bf16*   wkvb  = (__bf16*)(ws + 26 * MB);      // 4 MB   (stage A)
    _Float16* Opart = (_Float16*)(ws + 0);          // 16 MB  (stage B)
    float*    Lpart = (float*)(ws + 16 * MB);       // 0.5 MB (stage B)
    __bf16*   Yb    = (__bf16*)(ws + 17 * MB);      // 8 MB   (stage B)
    __bf16*   wob   = (__bf16*)(ws + 30 * MB);      // 2 MB
    __bf16*   Qp    = (__bf16*)(ws + 32 * MB);      // 8 MB
    __bf16*   Khd   = (__bf16*)(ws + 40 * MB);      // 16 MB  (stage C: gemm partials)
    __bf16*   Vhd   = (__bf16*)(ws + 56 * MB);      // 16 MB  (stage C: gemm partials)
    float*    Gp    = (float*)(ws + 40 * MB);       // 32 MB  (after attn: P0|P1)

    const float QSCALE = 0.125f * 1.4426950408889634f;

    f2b_multi<<<16384, 256, 0, stream>>>(q_f, kv_f, wq_f, wk_f, wv_f, wo_f,
                                         qb, kvb, wqb, wkvb, wob, QSCALE);

    proj_kernel<<<1280, 256, 0, stream>>>(qb, wqb, kvb, wkvb, Qp, Khd, Vhd, imp);

    attn_kernel<<<1024, 256, 0, stream>>>(Qp, Khd, Vhd, imp, Opart, Lpart);
    combine_kernel<<<2048, 256, 0, stream>>>(Opart, Lpart, Yb);

    gemm_out_kernel<<<dim3(16, 32), 256, 0, stream>>>(Yb, wob, Gp);
    combine2_kernel<<<4096, 256, 0, stream>>>(Gp, Gp + 4194304, (float*)d_out);
}